// Round 6
// baseline (305.344 us; speedup 1.0000x reference)
//
#include <hip/hip_runtime.h>
#include <math.h>
#include <limits.h>

// Problem constants (from reference): B=64, N=2048 predictions, M=64 gt boxes.
#define Bb 64
#define Nn 2048
#define Mm 64

// Exact cost expression shared by the cost-output tiles and the in-register
// hungarian scan. add/sub/abs/select only -> no contraction, bit-exact
// everywhere it is evaluated.
__device__ __forceinline__ float cost1(const float4 pb4, const float4 gb4,
                                       const float2 p2, const int g) {
    const float psv = (g == 0) ? p2.x : p2.y;
    float l1 = fabsf(pb4.x - gb4.x);
    l1 += fabsf(pb4.y - gb4.y);
    l1 += fabsf(pb4.z - gb4.z);
    l1 += fabsf(pb4.w - gb4.w);
    return (-psv) + l1;
}

// readlane lane 63 of an f64 (two b32 readlanes)
__device__ __forceinline__ double readlane_f64_63(double x) {
    const long long v = __double_as_longlong(x);
    const int lo = __builtin_amdgcn_readlane((int)v, 63);
    const int hi = __builtin_amdgcn_readlane((int)(v >> 32), 63);
    return __longlong_as_double(((long long)hi << 32) | (unsigned int)lo);
}

// readlane of an f64 from a dynamic (wave-uniform, SGPR) lane index
__device__ __forceinline__ double readlane_f64(double x, int sl) {
    const long long v = __double_as_longlong(x);
    const int lo = __builtin_amdgcn_readlane((int)v, sl);
    const int hi = __builtin_amdgcn_readlane((int)(v >> 32), sl);
    return __longlong_as_double(((long long)hi << 32) | (unsigned int)lo);
}

__device__ __forceinline__ float readlane_f32(float x, int sl) {
    return __int_as_float(__builtin_amdgcn_readlane(__float_as_int(x), sl));
}

// ---------------------------------------------------------------------------
// Layout-A cost tile: out[b][j][i] (B,N,M), float4 stores. blk in [0, Bb*32).
// Takes the 256-thread virtual tid explicitly so two tiles can run inside one
// 512-thread block. Identical float expression to all prior rounds (absmax 0).
// ---------------------------------------------------------------------------
__device__ __forceinline__ void cost_tileA_t(
    int blk, int t, const float* __restrict__ ps, const float* __restrict__ pb,
    const int* __restrict__ gs, const float* __restrict__ gb,
    float* __restrict__ out)
{
    const int b  = blk >> 5;            // 32 tiles per batch
    const int j0 = (blk & 31) << 6;     // tile j start
    const int sub = t & 15;
    const int grp = t >> 4;             // 0..15

    const int i4 = sub << 2;
    const int4   g4 = ((const int4*)(gs + b * Mm))[sub];
    const float4 gbq0 = ((const float4*)gb)[b * Mm + i4 + 0];
    const float4 gbq1 = ((const float4*)gb)[b * Mm + i4 + 1];
    const float4 gbq2 = ((const float4*)gb)[b * Mm + i4 + 2];
    const float4 gbq3 = ((const float4*)gb)[b * Mm + i4 + 3];
    #pragma unroll
    for (int r = 0; r < 4; ++r) {
        const int j = j0 + grp + (r << 4);
        const float2 p2  = ((const float2*)ps)[b * Nn + j];
        const float4 pb4 = ((const float4*)pb)[b * Nn + j];
        float4 o;
        o.x = cost1(pb4, gbq0, p2, g4.x);
        o.y = cost1(pb4, gbq1, p2, g4.y);
        o.z = cost1(pb4, gbq2, p2, g4.z);
        o.w = cost1(pb4, gbq3, p2, g4.w);
        ((float4*)(out + (((size_t)b * Nn + j) << 6)))[sub] = o;
    }
}

// Value-only f64 min compare-exchange via DPP on variable VAR.
// Invalid source lanes receive +inf via update_dpp's `old` operand.
#define MIN_DPP64(VAR, CTRL)                                                    \
  {                                                                             \
    const long long mb_ = __double_as_longlong(VAR);                            \
    const int lo_ = __builtin_amdgcn_update_dpp(0, (int)mb_, CTRL, 0xf, 0xf, false);            \
    const int hi_ = __builtin_amdgcn_update_dpp(0x7ff00000, (int)(mb_ >> 32), CTRL, 0xf, 0xf, false); \
    const double om_ = __longlong_as_double(((long long)hi_ << 32) | (unsigned int)lo_);        \
    VAR = fmin(VAR, om_);                                                       \
  }

// Barrier draining LDS ops only (lgkmcnt=0): vmcnt=63, expcnt=7, lgkmcnt=0.
__device__ __forceinline__ void barrier_lgkm() {
    asm volatile("" ::: "memory");
    __builtin_amdgcn_s_waitcnt(0xC07F);
    __builtin_amdgcn_s_barrier();
    asm volatile("" ::: "memory");
}

// Partial: exact f64 candidate value + packed (j, owner row i0):
// ji = (j << 7) | i0   (j in [1,2048] needs 12 bits; i0 in [0,64] fits 7).
struct alignas(16) Pt { double v; int ji; int pad; };

// ---------------------------------------------------------------------------
// Fused kernel, 512 threads/block (8 waves). Blocks [0, Bb/2) each run TWO
// batches of the (buggy-JV) reference loop: waves 0-3 -> batch 2*bid,
// waves 4-7 -> batch 2*bid+1. The two chains share one barrier per tick, so
// on every SIMD an A-wave and a B-wave interleave: one chain's DPP/LDS
// latency hides under the other's issue.
//
// Phase homogeneity (one barrier per tick, no epilogue barriers) comes from
// INCREMENTAL u/v updates: every thread computes the merged delta itself
// post-merge, so u accumulates per-iteration (same sequential rounding as
// the reference's u[p[used]] += delta), and each thread's owned cols keep
// vreal[] updated sequentially while marked (same rounding as v[used] -=
// delta). s_v / s_delta / s_j and the per-outer-i epilogue are eliminated.
// Chain state (marks, potentials, assignment) lives entirely in registers.
// Blocks [Bb/2, ...) each write TWO layout-A cost tiles.
// ---------------------------------------------------------------------------
__global__ __launch_bounds__(512, 1) void hungarian_fused(
    const float* __restrict__ ps, const float* __restrict__ pb,
    const int* __restrict__ gs, const float* __restrict__ gb,
    float* __restrict__ out, float* __restrict__ out_row,
    float* __restrict__ out_col)
{
    const int bid = blockIdx.x;
    if (bid >= Bb / 2) {                    // cost-output role: 2 tiles/block
        const int blk = ((bid - Bb / 2) << 1) + (threadIdx.x >> 8);
        cost_tileA_t(blk, threadIdx.x & 255, ps, pb, gs, gb, out);
        return;
    }

    // Hungarian waves outrank any co-resident cost waves in issue arbitration.
    __builtin_amdgcn_s_setprio(1);

    __shared__ Pt  s_part[2][2][4];         // [parity][group][slot]
    __shared__ int s_c4r[2][Mm];
    __shared__ int s_done[2];

    const int t = threadIdx.x;              // 0..511
    const int lane = t & 63;
    const int wave = t >> 6;                // 0..7
    const int grp = wave >> 2;              // 0 = batch A, 1 = batch B
    const int slot = wave & 3;              // wave within group
    const int tg = t & 255;                 // thread index within group
    const int b = (bid << 1) + grp;         // my batch
    const double INF = __builtin_inf();

    if (t < 2) s_done[t] = 0;               // visible after first tick barrier

    // ---- per-thread column data: my 8 cols q = 8*tg .. 8*tg+7 ----
    const float2* psb = (const float2*)(ps + (size_t)b * Nn * 2);
    const float4* pbb = (const float4*)(pb + (size_t)b * Nn * 4);
    float4 P[8]; float2 S[8];
    #pragma unroll
    for (int r = 0; r < 8; ++r) {
        P[r] = pbb[(tg << 3) + r];
        S[r] = psb[(tg << 3) + r];
    }
    // ---- per-lane gt data for row lane+1 (replicated in the group) ----
    const float4 rgb = ((const float4*)gb)[b * Mm + lane];
    const int    rg  = gs[b * Mm + lane];

    // ---- register-resident algorithm state ----
    double vv[8], vreal[8];                 // scan copy (-inf marks) / true v
    #pragma unroll
    for (int k = 0; k < 8; ++k) { vv[k] = 0.0; vreal[k] = 0.0; }
    double myu = 0.0;                       // u[lane+1], replicated in group
    int mycol = 0;                          // col assigned to row lane+1
    int mk = 0;                             // mark bits for my 8 cols
    bool inch = false;                      // my row is in the current chain
    bool done = false;
    int i = 1, i0 = 1;
    int par = 0;

    for (;;) {
        if (!done) {
            // ================= phase 1: scan + wave argmin =================
            const int sl = i0 - 1;          // uniform (loop var / readlane)
            float4 gb4;
            gb4.x = readlane_f32(rgb.x, sl);
            gb4.y = readlane_f32(rgb.y, sl);
            gb4.z = readlane_f32(rgb.z, sl);
            gb4.w = readlane_f32(rgb.w, sl);
            const int g = __builtin_amdgcn_readlane(rg, sl);
            const double u0 = readlane_f64(myu, sl);
            inch = inch || (lane + 1 == i0);    // row enters chain now

            double cur[8];
            #pragma unroll
            for (int k = 0; k < 8; ++k) {
                const float c = cost1(P[k], gb4, S[k], g);
                cur[k] = ((double)c - u0) - vv[k];   // ref f64 order
            }
            // in-thread tournament; strict < keeps left (lower j) on ties
            double v01 = cur[0]; int k01 = 0;
            if (cur[1] < v01) { v01 = cur[1]; k01 = 1; }
            double v23 = cur[2]; int k23 = 2;
            if (cur[3] < v23) { v23 = cur[3]; k23 = 3; }
            double v45 = cur[4]; int k45 = 4;
            if (cur[5] < v45) { v45 = cur[5]; k45 = 5; }
            double v67 = cur[6]; int k67 = 6;
            if (cur[7] < v67) { v67 = cur[7]; k67 = 7; }
            if (v23 < v01) { v01 = v23; k01 = k23; }
            if (v67 < v45) { v45 = v67; k45 = k67; }
            if (v45 < v01) { v01 = v45; k01 = k45; }
            const double bv = v01;
            const int bj = (tg << 3) + 1 + k01;

            // exact f64 value-only wave argmin; lowest lane = lowest j
            double mv = bv;
            MIN_DPP64(mv, 0x111)   // row_shr:1
            MIN_DPP64(mv, 0x112)   // row_shr:2
            MIN_DPP64(mv, 0x114)   // row_shr:4
            MIN_DPP64(mv, 0x118)   // row_shr:8
            MIN_DPP64(mv, 0x142)   // row_bcast:15
            MIN_DPP64(mv, 0x143)   // row_bcast:31
            const double wmin = readlane_f64_63(mv);
            const unsigned long long eq = __ballot(bv == wmin);
            const int l0 = (int)__builtin_ctzll(eq);
            const int bjw = __builtin_amdgcn_readlane(bj, l0);

            // owner of candidate col (cols uniquely owned; chains end on free)
            const unsigned long long mw = __ballot(mycol == bjw);
            const int i0w = mw ? (int)__builtin_ctzll(mw) + 1 : 0;
            if (lane == l0) {
                Pt p; p.v = bv; p.ji = (bjw << 7) | i0w; p.pad = 0;
                s_part[par][grp][slot] = p;
            }
        }
        barrier_lgkm();
        const int dA = s_done[0];           // flags from PREVIOUS tick
        const int dB = s_done[1];
        if (!done) {
            // ============ phase 2: 4-slot merge + state update ============
            const Pt pq = s_part[par][grp][lane & 3];
            double mv2 = pq.v;
            MIN_DPP64(mv2, 0xB1)   // quad_perm [1,0,3,2]
            MIN_DPP64(mv2, 0x4E)   // quad_perm [2,3,0,1]
            const unsigned long long wb = __ballot(pq.v == mv2);
            const int wsel = (int)__builtin_ctzll(wb);  // lowest slot = lowest j
            const int jiw = __builtin_amdgcn_readlane(pq.ji, wsel);
            const double delta = readlane_f64(pq.v, wsel);
            const int fjc = jiw >> 7;
            const int fi0 = jiw & 127;

            // u[rows in chain] += delta   (per-iteration, sequential = ref)
            myu += inch ? delta : 0.0;
            // v[used cols] -= delta       (per-iteration, sequential = ref)
            if (mk) {
                #pragma unroll
                for (int k = 0; k < 8; ++k)
                    vreal[k] -= ((mk >> k) & 1) ? delta : 0.0;
            }

            if (fi0 == 0) {                 // free col -> chain done (uniform)
                if (lane == i - 1) mycol = fjc;      // augment (way==0 bug)
                #pragma unroll
                for (int k = 0; k < 8; ++k) vv[k] = vreal[k];  // clear marks
                mk = 0; inch = false;
                ++i; i0 = i;
                if (i > Mm) {
                    done = true;
                    if (tg == 0) s_done[grp] = 1;    // read next tick
                }
            } else {
                i0 = fi0;                   // owning row continues the chain
                if (((fjc - 1) >> 3) == tg) {        // mark col used (mine)
                    const int km = (fjc - 1) & 7;
                    #pragma unroll
                    for (int k = 0; k < 8; ++k)
                        if (k == km) vv[k] = -INF;
                    mk |= 1 << km;
                }
            }
        }
        if (dA && dB) break;                // both groups were done pre-tick
        par ^= 1;
    }

    // Emit row_ind (sorted pred idx) / col_ind (gt idx ordered by pred idx).
    if (wave == 0) s_c4r[0][lane] = mycol - 1;   // batch A, rows 1..64
    if (wave == 4) s_c4r[1][lane] = mycol - 1;   // batch B
    __syncthreads();
    if (t < 128) {
        const int gq = t >> 6, r = t & 63;
        const int my = s_c4r[gq][r];
        int rank = 0;
        #pragma unroll 4
        for (int q = 0; q < Mm; ++q) rank += (s_c4r[gq][q] < my);
        const int bb = (bid << 1) + gq;
        out_row[bb * Mm + rank] = (float)my;
        out_col[bb * Mm + rank] = (float)r;
    }
}

extern "C" void kernel_launch(void* const* d_in, const int* in_sizes, int n_in,
                              void* d_out, int out_size, void* d_ws, size_t ws_size,
                              hipStream_t stream) {
    const float* ps = (const float*)d_in[0];   // (64,2048,2) f32
    const float* pb = (const float*)d_in[1];   // (64,2048,4) f32
    const int*   gs = (const int*)d_in[2];     // (64,64) i32
    const float* gb = (const float*)d_in[3];   // (64,64,4) f32
    float* out = (float*)d_out;
    float* out_row = out + (size_t)Bb * Nn * Mm;          // 8388608
    float* out_col = out_row + Bb * Mm;                    // +4096

    (void)d_ws; (void)ws_size;
    // Single fused dispatch: 32 dual-batch hungarian blocks (waves 0-3 =
    // batch 2k, waves 4-7 = batch 2k+1) + 1024 cost blocks (2 tiles each).
    hungarian_fused<<<Bb / 2 + Bb * (Nn / 128), 512, 0, stream>>>(
        ps, pb, gs, gb, out, out_row, out_col);
}

// Round 7
// 254.115 us; speedup vs baseline: 1.2016x; 1.2016x over previous
//
#include <hip/hip_runtime.h>
#include <math.h>
#include <limits.h>

// Problem constants (from reference): B=64, N=2048 predictions, M=64 gt boxes.
#define Bb 64
#define Nn 2048
#define Mm 64

// Exact cost expression shared by the cost-output tiles and the in-register
// hungarian scan. add/sub/abs/select only -> no contraction, bit-exact
// everywhere it is evaluated.
__device__ __forceinline__ float cost1(const float4 pb4, const float4 gb4,
                                       const float2 p2, const int g) {
    const float psv = (g == 0) ? p2.x : p2.y;
    float l1 = fabsf(pb4.x - gb4.x);
    l1 += fabsf(pb4.y - gb4.y);
    l1 += fabsf(pb4.z - gb4.z);
    l1 += fabsf(pb4.w - gb4.w);
    return (-psv) + l1;
}

// readlane lane 63 of an f64 (two b32 readlanes)
__device__ __forceinline__ double readlane_f64_63(double x) {
    const long long v = __double_as_longlong(x);
    const int lo = __builtin_amdgcn_readlane((int)v, 63);
    const int hi = __builtin_amdgcn_readlane((int)(v >> 32), 63);
    return __longlong_as_double(((long long)hi << 32) | (unsigned int)lo);
}

// readlane of an f64 from a dynamic (wave-uniform, SGPR) lane index
__device__ __forceinline__ double readlane_f64(double x, int sl) {
    const long long v = __double_as_longlong(x);
    const int lo = __builtin_amdgcn_readlane((int)v, sl);
    const int hi = __builtin_amdgcn_readlane((int)(v >> 32), sl);
    return __longlong_as_double(((long long)hi << 32) | (unsigned int)lo);
}

__device__ __forceinline__ float readlane_f32(float x, int sl) {
    return __int_as_float(__builtin_amdgcn_readlane(__float_as_int(x), sl));
}

// ---------------------------------------------------------------------------
// Layout-A cost tile: out[b][j][i] (B,N,M), float4 stores. blk in [0, Bb*32).
// Takes the 256-thread virtual tid explicitly so two tiles can run inside one
// 512-thread block. Identical float expression to all prior rounds (absmax 0).
// ---------------------------------------------------------------------------
__device__ __forceinline__ void cost_tileA_t(
    int blk, int t, const float* __restrict__ ps, const float* __restrict__ pb,
    const int* __restrict__ gs, const float* __restrict__ gb,
    float* __restrict__ out)
{
    const int b  = blk >> 5;            // 32 tiles per batch
    const int j0 = (blk & 31) << 6;     // tile j start
    const int sub = t & 15;
    const int grp = t >> 4;             // 0..15

    const int i4 = sub << 2;
    const int4   g4 = ((const int4*)(gs + b * Mm))[sub];
    const float4 gbq0 = ((const float4*)gb)[b * Mm + i4 + 0];
    const float4 gbq1 = ((const float4*)gb)[b * Mm + i4 + 1];
    const float4 gbq2 = ((const float4*)gb)[b * Mm + i4 + 2];
    const float4 gbq3 = ((const float4*)gb)[b * Mm + i4 + 3];
    #pragma unroll
    for (int r = 0; r < 4; ++r) {
        const int j = j0 + grp + (r << 4);
        const float2 p2  = ((const float2*)ps)[b * Nn + j];
        const float4 pb4 = ((const float4*)pb)[b * Nn + j];
        float4 o;
        o.x = cost1(pb4, gbq0, p2, g4.x);
        o.y = cost1(pb4, gbq1, p2, g4.y);
        o.z = cost1(pb4, gbq2, p2, g4.z);
        o.w = cost1(pb4, gbq3, p2, g4.w);
        ((float4*)(out + (((size_t)b * Nn + j) << 6)))[sub] = o;
    }
}

// Value-only f64 min compare-exchange via DPP on variable VAR.
// Invalid source lanes receive +inf via update_dpp's `old` operand.
#define MIN_DPP64(VAR, CTRL)                                                    \
  {                                                                             \
    const long long mb_ = __double_as_longlong(VAR);                            \
    const int lo_ = __builtin_amdgcn_update_dpp(0, (int)mb_, CTRL, 0xf, 0xf, false);            \
    const int hi_ = __builtin_amdgcn_update_dpp(0x7ff00000, (int)(mb_ >> 32), CTRL, 0xf, 0xf, false); \
    const double om_ = __longlong_as_double(((long long)hi_ << 32) | (unsigned int)lo_);        \
    VAR = fmin(VAR, om_);                                                       \
  }

// Barrier draining LDS ops only (lgkmcnt=0): vmcnt=63, expcnt=7, lgkmcnt=0.
__device__ __forceinline__ void barrier_lgkm() {
    asm volatile("" ::: "memory");
    __builtin_amdgcn_s_waitcnt(0xC07F);
    __builtin_amdgcn_s_barrier();
    asm volatile("" ::: "memory");
}

// Partial: exact f64 candidate value + candidate col j (winner lane's own).
struct alignas(16) Pt { double v; int j; int pad; };

// ---------------------------------------------------------------------------
// Fused kernel, 512 threads/block (8 waves). Blocks [0,Bb) run the
// (buggy-JV) reference loop entirely from REGISTERS -- round-4 topology
// (single batch, 8 waves, 4 cols/thread, exact f64 DPP reduces) combined
// with round-6's register-incremental u/v state:
//   - per tick:   myu += inch ? delta : 0        (ref: u[p[used]] += delta)
//                 vreal[k] -= delta while marked (ref: v[used] -= delta)
//   - per outer end: vv = vreal, mk=0 (register-only; NO barriers, NO s_v)
// Exactly ONE barrier per chain iteration. s_v/s_delta/s_j and the two
// per-outer epilogue barriers + suffix loops + LDS reload are eliminated.
// Owner resolution (which row owns the winning col) moved post-merge:
// ballot(mycol == fjc) -- mycol is replicated in every wave.
// Blocks [Bb, ...) each write TWO layout-A cost tiles.
// ---------------------------------------------------------------------------
__global__ __launch_bounds__(512, 1) void hungarian_fused(
    const float* __restrict__ ps, const float* __restrict__ pb,
    const int* __restrict__ gs, const float* __restrict__ gb,
    float* __restrict__ out, float* __restrict__ out_row,
    float* __restrict__ out_col)
{
    const int bid = blockIdx.x;
    if (bid >= Bb) {                        // cost-output role: 2 tiles/block
        const int blk = ((bid - Bb) << 1) + (threadIdx.x >> 8);
        cost_tileA_t(blk, threadIdx.x & 255, ps, pb, gs, gb, out);
        return;
    }

    // Hungarian waves outrank any co-resident cost waves in issue arbitration.
    __builtin_amdgcn_s_setprio(1);

    __shared__ Pt  s_part[2][8];            // [parity][wave]
    __shared__ int s_c4r[Mm];

    const int b = bid;
    const int t = threadIdx.x;              // 0..511
    const int lane = t & 63;
    const int wave = t >> 6;                // 0..7
    const double INF = __builtin_inf();

    // ---- per-thread column data: my 4 cols q = 4t..4t+3 (row-invariant) ----
    const float2* psb = (const float2*)(ps + (size_t)b * Nn * 2);
    const float4* pbb = (const float4*)(pb + (size_t)b * Nn * 4);
    float4 P[4]; float2 S[4];
    #pragma unroll
    for (int r = 0; r < 4; ++r) {
        P[r] = pbb[(t << 2) + r];
        S[r] = psb[(t << 2) + r];
    }
    // ---- per-lane gt data for row lane+1 (replicated in every wave) ----
    const float4 rgb = ((const float4*)gb)[b * Mm + lane];
    const int    rg  = gs[b * Mm + lane];

    // ---- register-resident algorithm state ----
    double vv[4], vreal[4];                 // scan copy (-inf marks) / true v
    #pragma unroll
    for (int k = 0; k < 4; ++k) { vv[k] = 0.0; vreal[k] = 0.0; }
    double myu = 0.0;                       // u[lane+1], replicated per wave
    int mycol = 0;                          // col assigned to row lane+1
    int mk = 0;                             // mark bits for my 4 cols
    bool inch = false;                      // my row is in the current chain
    int i = 1, i0 = 1;
    int par = 0;

    for (;;) {
        // ================= phase 1: scan + wave argmin =================
        const int sl = i0 - 1;              // wave-uniform scalar
        float4 gb4;
        gb4.x = readlane_f32(rgb.x, sl);
        gb4.y = readlane_f32(rgb.y, sl);
        gb4.z = readlane_f32(rgb.z, sl);
        gb4.w = readlane_f32(rgb.w, sl);
        const int g = __builtin_amdgcn_readlane(rg, sl);
        const double u0 = readlane_f64(myu, sl);
        inch = inch || (lane + 1 == i0);    // row i0 enters the chain now

        double cur[4];
        #pragma unroll
        for (int k = 0; k < 4; ++k) {
            const float c = cost1(P[k], gb4, S[k], g);
            cur[k] = ((double)c - u0) - vv[k];   // ref f64 order
        }
        // in-thread tournament; strict < keeps left (lower j) on ties
        double v01 = cur[0]; int k01 = 0;
        if (cur[1] < v01) { v01 = cur[1]; k01 = 1; }
        double v23 = cur[2]; int k23 = 2;
        if (cur[3] < v23) { v23 = cur[3]; k23 = 3; }
        if (v23 < v01) { v01 = v23; k01 = k23; }
        const double bv = v01;
        const int bj = (t << 2) + 1 + k01;

        // exact f64 value-only wave argmin; lowest lane = lowest j
        double mv = bv;
        MIN_DPP64(mv, 0x111)   // row_shr:1
        MIN_DPP64(mv, 0x112)   // row_shr:2
        MIN_DPP64(mv, 0x114)   // row_shr:4
        MIN_DPP64(mv, 0x118)   // row_shr:8
        MIN_DPP64(mv, 0x142)   // row_bcast:15
        MIN_DPP64(mv, 0x143)   // row_bcast:31
        const double wmin = readlane_f64_63(mv);
        const unsigned long long eq = __ballot(bv == wmin);
        const int l0 = (int)__builtin_ctzll(eq);
        if (lane == l0) {                   // winner writes its OWN (v, j)
            Pt p; p.v = bv; p.j = bj; p.pad = 0;
            s_part[par][wave] = p;
        }
        barrier_lgkm();

        // ============ phase 2: 8-slot merge + state update ============
        const Pt pq = s_part[par][lane & 7];
        double mv2 = pq.v;
        MIN_DPP64(mv2, 0xB1)    // quad_perm [1,0,3,2] : pair 1
        MIN_DPP64(mv2, 0x4E)    // quad_perm [2,3,0,1] : pair 2
        MIN_DPP64(mv2, 0x124)   // row_ror:4           : pair 4 (replicas OK)
        const unsigned long long wb = __ballot(pq.v == mv2);
        const int wsel = (int)__builtin_ctzll(wb);  // lowest wave = lowest j
        const int fjc = __builtin_amdgcn_readlane(pq.j, wsel);
        const double delta = readlane_f64(pq.v, wsel);

        // owner of the winning col (0 = free); mycol replicated in all waves
        const unsigned long long ow = __ballot(mycol == fjc);
        const int fi0 = ow ? (int)__builtin_ctzll(ow) + 1 : 0;

        // u[rows in chain] += delta   (per-iteration, sequential = ref)
        myu += inch ? delta : 0.0;
        // v[used cols] -= delta       (per-iteration, sequential = ref)
        if (mk) {
            #pragma unroll
            for (int k = 0; k < 4; ++k)
                vreal[k] -= ((mk >> k) & 1) ? delta : 0.0;
        }

        if (fi0 == 0) {                     // free col -> chain done (uniform)
            if (lane == i - 1) mycol = fjc;          // augment (way==0 bug)
            #pragma unroll
            for (int k = 0; k < 4; ++k) vv[k] = vreal[k];  // clear marks
            mk = 0; inch = false;
            ++i;
            if (i > Mm) break;
            i0 = i;
        } else {
            i0 = fi0;                       // owning row continues the chain
            if (((fjc - 1) >> 2) == t) {    // mark col used (mine)
                const int km = (fjc - 1) & 3;
                #pragma unroll
                for (int k = 0; k < 4; ++k)
                    if (k == km) vv[k] = -INF;
                mk |= 1 << km;
            }
        }
        par ^= 1;
    }

    // Emit row_ind (sorted pred idx) / col_ind (gt idx ordered by pred idx).
    if (wave == 0) s_c4r[lane] = mycol - 1;  // row lane+1 -> 0-based pred idx
    __syncthreads();
    if (t < Mm) {
        const int my = s_c4r[t];
        int rank = 0;
        #pragma unroll 4
        for (int q = 0; q < Mm; ++q) rank += (s_c4r[q] < my);
        out_row[b * Mm + rank] = (float)my;
        out_col[b * Mm + rank] = (float)t;
    }
}

extern "C" void kernel_launch(void* const* d_in, const int* in_sizes, int n_in,
                              void* d_out, int out_size, void* d_ws, size_t ws_size,
                              hipStream_t stream) {
    const float* ps = (const float*)d_in[0];   // (64,2048,2) f32
    const float* pb = (const float*)d_in[1];   // (64,2048,4) f32
    const int*   gs = (const int*)d_in[2];     // (64,64) i32
    const float* gb = (const float*)d_in[3];   // (64,64,4) f32
    float* out = (float*)d_out;
    float* out_row = out + (size_t)Bb * Nn * Mm;          // 8388608
    float* out_col = out_row + Bb * Mm;                    // +4096

    (void)d_ws; (void)ws_size;
    // Single fused dispatch: 64 register-resident hungarian blocks (8 waves,
    // 4 cols/thread) + 1024 cost blocks (2 verified 64-j tiles each).
    hungarian_fused<<<Bb + Bb * (Nn / 128), 512, 0, stream>>>(
        ps, pb, gs, gb, out, out_row, out_col);
}

// Round 8
// 250.388 us; speedup vs baseline: 1.2195x; 1.0149x over previous
//
#include <hip/hip_runtime.h>
#include <math.h>
#include <limits.h>

// Problem constants (from reference): B=64, N=2048 predictions, M=64 gt boxes.
#define Bb 64
#define Nn 2048
#define Mm 64

// Exact cost expression shared by the cost-output tiles and the in-register
// hungarian scan. add/sub/abs/select only -> no contraction, bit-exact
// everywhere it is evaluated.
__device__ __forceinline__ float cost1(const float4 pb4, const float4 gb4,
                                       const float2 p2, const int g) {
    const float psv = (g == 0) ? p2.x : p2.y;
    float l1 = fabsf(pb4.x - gb4.x);
    l1 += fabsf(pb4.y - gb4.y);
    l1 += fabsf(pb4.z - gb4.z);
    l1 += fabsf(pb4.w - gb4.w);
    return (-psv) + l1;
}

// readlane lane 63 of an f64 (two b32 readlanes)
__device__ __forceinline__ double readlane_f64_63(double x) {
    const long long v = __double_as_longlong(x);
    const int lo = __builtin_amdgcn_readlane((int)v, 63);
    const int hi = __builtin_amdgcn_readlane((int)(v >> 32), 63);
    return __longlong_as_double(((long long)hi << 32) | (unsigned int)lo);
}

// readlane of an f64 from a dynamic (wave-uniform, SGPR) lane index
__device__ __forceinline__ double readlane_f64(double x, int sl) {
    const long long v = __double_as_longlong(x);
    const int lo = __builtin_amdgcn_readlane((int)v, sl);
    const int hi = __builtin_amdgcn_readlane((int)(v >> 32), sl);
    return __longlong_as_double(((long long)hi << 32) | (unsigned int)lo);
}

__device__ __forceinline__ float readlane_f32(float x, int sl) {
    return __int_as_float(__builtin_amdgcn_readlane(__float_as_int(x), sl));
}

// ---------------------------------------------------------------------------
// Layout-A cost tile: out[b][j][i] (B,N,M), float4 stores. blk in [0, Bb*32).
// Takes the 256-thread virtual tid explicitly so two tiles can run inside one
// 512-thread block. Identical float expression to all prior rounds (absmax 0).
// ---------------------------------------------------------------------------
__device__ __forceinline__ void cost_tileA_t(
    int blk, int t, const float* __restrict__ ps, const float* __restrict__ pb,
    const int* __restrict__ gs, const float* __restrict__ gb,
    float* __restrict__ out)
{
    const int b  = blk >> 5;            // 32 tiles per batch
    const int j0 = (blk & 31) << 6;     // tile j start
    const int sub = t & 15;
    const int grp = t >> 4;             // 0..15

    const int i4 = sub << 2;
    const int4   g4 = ((const int4*)(gs + b * Mm))[sub];
    const float4 gbq0 = ((const float4*)gb)[b * Mm + i4 + 0];
    const float4 gbq1 = ((const float4*)gb)[b * Mm + i4 + 1];
    const float4 gbq2 = ((const float4*)gb)[b * Mm + i4 + 2];
    const float4 gbq3 = ((const float4*)gb)[b * Mm + i4 + 3];
    #pragma unroll
    for (int r = 0; r < 4; ++r) {
        const int j = j0 + grp + (r << 4);
        const float2 p2  = ((const float2*)ps)[b * Nn + j];
        const float4 pb4 = ((const float4*)pb)[b * Nn + j];
        float4 o;
        o.x = cost1(pb4, gbq0, p2, g4.x);
        o.y = cost1(pb4, gbq1, p2, g4.y);
        o.z = cost1(pb4, gbq2, p2, g4.z);
        o.w = cost1(pb4, gbq3, p2, g4.w);
        ((float4*)(out + (((size_t)b * Nn + j) << 6)))[sub] = o;
    }
}

// Value-only f64 min compare-exchange via DPP on variable VAR.
// Invalid source lanes receive +inf via update_dpp's `old` operand.
#define MIN_DPP64(VAR, CTRL)                                                    \
  {                                                                             \
    const long long mb_ = __double_as_longlong(VAR);                            \
    const int lo_ = __builtin_amdgcn_update_dpp(0, (int)mb_, CTRL, 0xf, 0xf, false);            \
    const int hi_ = __builtin_amdgcn_update_dpp(0x7ff00000, (int)(mb_ >> 32), CTRL, 0xf, 0xf, false); \
    const double om_ = __longlong_as_double(((long long)hi_ << 32) | (unsigned int)lo_);        \
    VAR = fmin(VAR, om_);                                                       \
  }

// Barrier draining LDS ops only (lgkmcnt=0): vmcnt=63, expcnt=7, lgkmcnt=0.
__device__ __forceinline__ void barrier_lgkm() {
    asm volatile("" ::: "memory");
    __builtin_amdgcn_s_waitcnt(0xC07F);
    __builtin_amdgcn_s_barrier();
    asm volatile("" ::: "memory");
}

// Partial: exact f64 candidate value + candidate col j (winner lane's own).
struct alignas(16) Pt { double v; int j; int pad; };

// ---------------------------------------------------------------------------
// Fused kernel, 512 threads/block (8 waves). Blocks [0,Bb) run the
// (buggy-JV) reference loop entirely from REGISTERS: thread t owns 4 cols
// (4t+1..4t+4), per-row gt data broadcast via v_readlane, incremental u/v
// state in registers, ONE barrier per chain tick.
//
// Round-8 cut: delta is taken directly from the merged min register mv2 --
// after the 3 DPP stages (0xB1 / 0x4E / row_ror:4 over the 8 slots, which
// the replicated lane groups make a complete 8-way fold) EVERY lane holds
// the exact minimum VALUE, bit-identical to the winning slot's value (fmin
// over finite doubles; the only bit ambiguity is +/-0, inert in all
// downstream adds and compares). This removes the post-merge
// readlane_f64(pq.v, wsel) from the serial tick. Index selection (wsel via
// ballot, lowest wave = lowest j) is unchanged, so tie-breaks stay exact.
// Blocks [Bb, ...) each write TWO layout-A cost tiles.
// ---------------------------------------------------------------------------
__global__ __launch_bounds__(512, 1) void hungarian_fused(
    const float* __restrict__ ps, const float* __restrict__ pb,
    const int* __restrict__ gs, const float* __restrict__ gb,
    float* __restrict__ out, float* __restrict__ out_row,
    float* __restrict__ out_col)
{
    const int bid = blockIdx.x;
    if (bid >= Bb) {                        // cost-output role: 2 tiles/block
        const int blk = ((bid - Bb) << 1) + (threadIdx.x >> 8);
        cost_tileA_t(blk, threadIdx.x & 255, ps, pb, gs, gb, out);
        return;
    }

    // Hungarian waves outrank any co-resident cost waves in issue arbitration.
    __builtin_amdgcn_s_setprio(1);

    __shared__ Pt  s_part[2][8];            // [parity][wave]
    __shared__ int s_c4r[Mm];

    const int b = bid;
    const int t = threadIdx.x;              // 0..511
    const int lane = t & 63;
    const int wave = t >> 6;                // 0..7
    const double INF = __builtin_inf();

    // ---- per-thread column data: my 4 cols q = 4t..4t+3 (row-invariant) ----
    const float2* psb = (const float2*)(ps + (size_t)b * Nn * 2);
    const float4* pbb = (const float4*)(pb + (size_t)b * Nn * 4);
    float4 P[4]; float2 S[4];
    #pragma unroll
    for (int r = 0; r < 4; ++r) {
        P[r] = pbb[(t << 2) + r];
        S[r] = psb[(t << 2) + r];
    }
    // ---- per-lane gt data for row lane+1 (replicated in every wave) ----
    const float4 rgb = ((const float4*)gb)[b * Mm + lane];
    const int    rg  = gs[b * Mm + lane];

    // ---- register-resident algorithm state ----
    double vv[4], vreal[4];                 // scan copy (-inf marks) / true v
    #pragma unroll
    for (int k = 0; k < 4; ++k) { vv[k] = 0.0; vreal[k] = 0.0; }
    double myu = 0.0;                       // u[lane+1], replicated per wave
    int mycol = 0;                          // col assigned to row lane+1
    int mk = 0;                             // mark bits for my 4 cols
    bool inch = false;                      // my row is in the current chain
    int i = 1, i0 = 1;
    int par = 0;

    for (;;) {
        // ================= phase 1: scan + wave argmin =================
        const int sl = i0 - 1;              // wave-uniform scalar
        float4 gb4;
        gb4.x = readlane_f32(rgb.x, sl);
        gb4.y = readlane_f32(rgb.y, sl);
        gb4.z = readlane_f32(rgb.z, sl);
        gb4.w = readlane_f32(rgb.w, sl);
        const int g = __builtin_amdgcn_readlane(rg, sl);
        const double u0 = readlane_f64(myu, sl);
        inch = inch || (lane + 1 == i0);    // row i0 enters the chain now

        double cur[4];
        #pragma unroll
        for (int k = 0; k < 4; ++k) {
            const float c = cost1(P[k], gb4, S[k], g);
            cur[k] = ((double)c - u0) - vv[k];   // ref f64 order
        }
        // in-thread tournament; strict < keeps left (lower j) on ties
        double v01 = cur[0]; int k01 = 0;
        if (cur[1] < v01) { v01 = cur[1]; k01 = 1; }
        double v23 = cur[2]; int k23 = 2;
        if (cur[3] < v23) { v23 = cur[3]; k23 = 3; }
        if (v23 < v01) { v01 = v23; k01 = k23; }
        const double bv = v01;
        const int bj = (t << 2) + 1 + k01;

        // exact f64 value-only wave argmin; lowest lane = lowest j
        double mv = bv;
        MIN_DPP64(mv, 0x111)   // row_shr:1
        MIN_DPP64(mv, 0x112)   // row_shr:2
        MIN_DPP64(mv, 0x114)   // row_shr:4
        MIN_DPP64(mv, 0x118)   // row_shr:8
        MIN_DPP64(mv, 0x142)   // row_bcast:15
        MIN_DPP64(mv, 0x143)   // row_bcast:31
        const double wmin = readlane_f64_63(mv);
        const unsigned long long eq = __ballot(bv == wmin);
        const int l0 = (int)__builtin_ctzll(eq);
        if (lane == l0) {                   // winner writes its OWN (v, j)
            Pt p; p.v = bv; p.j = bj; p.pad = 0;
            s_part[par][wave] = p;
        }
        barrier_lgkm();

        // ============ phase 2: 8-slot merge + state update ============
        const Pt pq = s_part[par][lane & 7];
        double mv2 = pq.v;
        MIN_DPP64(mv2, 0xB1)    // quad_perm [1,0,3,2] : pair 1
        MIN_DPP64(mv2, 0x4E)    // quad_perm [2,3,0,1] : pair 2
        MIN_DPP64(mv2, 0x124)   // row_ror:4           : pair 4 (replicas OK)
        // mv2 now holds the exact 8-way min in EVERY lane == delta.
        const double delta = mv2;
        const unsigned long long wb = __ballot(pq.v == mv2);
        const int wsel = (int)__builtin_ctzll(wb);  // lowest wave = lowest j
        const int fjc = __builtin_amdgcn_readlane(pq.j, wsel);

        // owner of the winning col (0 = free); mycol replicated in all waves
        const unsigned long long ow = __ballot(mycol == fjc);
        const int fi0 = ow ? (int)__builtin_ctzll(ow) + 1 : 0;

        // u[rows in chain] += delta   (per-iteration, sequential = ref)
        myu += inch ? delta : 0.0;
        // v[used cols] -= delta       (per-iteration, sequential = ref)
        if (mk) {
            #pragma unroll
            for (int k = 0; k < 4; ++k)
                vreal[k] -= ((mk >> k) & 1) ? delta : 0.0;
        }

        if (fi0 == 0) {                     // free col -> chain done (uniform)
            if (lane == i - 1) mycol = fjc;          // augment (way==0 bug)
            #pragma unroll
            for (int k = 0; k < 4; ++k) vv[k] = vreal[k];  // clear marks
            mk = 0; inch = false;
            ++i;
            if (i > Mm) break;
            i0 = i;
        } else {
            i0 = fi0;                       // owning row continues the chain
            if (((fjc - 1) >> 2) == t) {    // mark col used (mine)
                const int km = (fjc - 1) & 3;
                #pragma unroll
                for (int k = 0; k < 4; ++k)
                    if (k == km) vv[k] = -INF;
                mk |= 1 << km;
            }
        }
        par ^= 1;
    }

    // Emit row_ind (sorted pred idx) / col_ind (gt idx ordered by pred idx).
    if (wave == 0) s_c4r[lane] = mycol - 1;  // row lane+1 -> 0-based pred idx
    __syncthreads();
    if (t < Mm) {
        const int my = s_c4r[t];
        int rank = 0;
        #pragma unroll 4
        for (int q = 0; q < Mm; ++q) rank += (s_c4r[q] < my);
        out_row[b * Mm + rank] = (float)my;
        out_col[b * Mm + rank] = (float)t;
    }
}

extern "C" void kernel_launch(void* const* d_in, const int* in_sizes, int n_in,
                              void* d_out, int out_size, void* d_ws, size_t ws_size,
                              hipStream_t stream) {
    const float* ps = (const float*)d_in[0];   // (64,2048,2) f32
    const float* pb = (const float*)d_in[1];   // (64,2048,4) f32
    const int*   gs = (const int*)d_in[2];     // (64,64) i32
    const float* gb = (const float*)d_in[3];   // (64,64,4) f32
    float* out = (float*)d_out;
    float* out_row = out + (size_t)Bb * Nn * Mm;          // 8388608
    float* out_col = out_row + Bb * Mm;                    // +4096

    (void)d_ws; (void)ws_size;
    // Single fused dispatch: 64 register-resident hungarian blocks (8 waves,
    // 4 cols/thread) + 1024 cost blocks (2 verified 64-j tiles each).
    hungarian_fused<<<Bb + Bb * (Nn / 128), 512, 0, stream>>>(
        ps, pb, gs, gb, out, out_row, out_col);
}